// Round 3
// baseline (4609.927 us; speedup 1.0000x reference)
//
#include <hip/hip_runtime.h>
#include <hip/hip_bf16.h>
#include <stdint.h>

// Problem constants
#define B_   64
#define S_   512
#define DIN  512
#define DH   1024
#define NBG  4               // batch groups (16 rows each)
#define NCG  16              // col groups (64 cols each)
#define BBLK 16
#define CBLK 64
#define NKC  48              // 16 x-chunks + 32 h-chunks of K=32

typedef __bf16 bf16x8 __attribute__((ext_vector_type(8)));
typedef float f32x4 __attribute__((ext_vector_type(4)));
typedef unsigned short ushort8v __attribute__((ext_vector_type(8)));
typedef unsigned short ushort4v __attribute__((ext_vector_type(4)));
typedef unsigned long long ull;

static __device__ __forceinline__ unsigned short f2bf(float f) {
    union { __bf16 b; unsigned short u; } v; v.b = (__bf16)f; return v.u;
}
static __device__ __forceinline__ float fast_tanh(float x) {
    float e = __expf(2.0f * x);
    return 1.0f - 2.0f / (e + 1.0f);
}

// ---------------- convert x (fp32 -> bf16) ----------------
__global__ void k_cvt_bf16(const float* __restrict__ src,
                           unsigned short* __restrict__ dst, int n4) {
    int i = blockIdx.x * blockDim.x + threadIdx.x;
    if (i < n4) {
        float4 v = ((const float4*)src)[i];
        ushort4v o;
        o.x = f2bf(v.x); o.y = f2bf(v.y); o.z = f2bf(v.z); o.w = f2bf(v.w);
        ((ushort4v*)dst)[i] = o;
    }
}

// ------- swizzle W (fp32 [1536][1024]) into B-fragment order, bf16 -------
// layout: [kc(48)][ntg(64)][lane(64)][8] ; frag elem i = W[kc*32+q*8+i][ntg*16+n16]
__global__ void k_swz_w(const float* __restrict__ W,
                        unsigned short* __restrict__ dst) {
    int u = blockIdx.x * blockDim.x + threadIdx.x;   // 196608
    int lane = u & 63;
    int ntg  = (u >> 6) & 63;
    int kc   = u >> 12;
    int q = lane >> 4, n16 = lane & 15;
    int k0 = kc * 32 + q * 8;
    int n  = ntg * 16 + n16;
    ushort8v o;
#pragma unroll
    for (int i = 0; i < 8; ++i) o[i] = f2bf(W[(size_t)(k0 + i) * DH + n]);
    *(ushort8v*)(dst + (size_t)u * 8) = o;
}

// ---------------- persistent recurrence kernel ----------------
// LDS: x-W frags 64 KB + h double-buffer 2*16*1032 ushorts (66048 B)
#define H_PITCH 1032                 // ushorts per row (1024 + 8 pad)
#define H_BUF   (16 * H_PITCH)       // 16512 ushorts per buffer
#define LDS_X_USH 32768              // 16 kc * 4 nt * 64 lanes * 8
#define SMEM_BYTES (LDS_X_USH * 2 + 2 * H_BUF * 2)   // 131584

__global__ __launch_bounds__(256, 1) void k_rnn(
    const unsigned short* __restrict__ xb,    // [B][S][DIN] bf16
    const unsigned short* __restrict__ wswz,  // swizzled W bf16
    const float* __restrict__ h0,             // [B][DH] fp32
    const float* __restrict__ bias,           // [DH] fp32
    float* __restrict__ out,                  // outs [B][S][DH] + h_last [B][DH]
    unsigned short* ring,                     // [2][B][DH] bf16 row-major
    int* flags)                               // [NBG][S][64] per producer-wave
{
    extern __shared__ char smem[];
    unsigned short* ldsX = (unsigned short*)smem;                 // x-part W frags
    unsigned short* ldsH = (unsigned short*)(smem + LDS_X_USH * 2);

    const int tid = threadIdx.x;
    const int bg = blockIdx.x >> 4;
    const int cg = blockIdx.x & 15;
    const int b0 = bg * BBLK;
    const int c0 = cg * CBLK;
    const int lane = tid & 63;
    const int wv = tid >> 6;          // = local n-tile
    const int q = lane >> 4;
    const int m16 = lane & 15;

    // ---- one-time: stage x-part W frags (kc 0..15, 4 local ntiles) into LDS
#pragma unroll
    for (int i = 0; i < 16; ++i) {
        int c = i * 256 + tid;                 // 4096 frags
        int kc = c >> 8, l = (c >> 6) & 3, ln = c & 63;
        *(ushort8v*)(ldsX + ((kc * 4 + l) * 64 + ln) * 8) =
            *(const ushort8v*)(wswz + ((size_t)(kc * 64 + cg * 4 + l) * 64 + ln) * 8);
    }

    // ---- one-time: h-part W frags (kc 16..47, own ntile) into registers
    bf16x8 wh[32];
#pragma unroll
    for (int j = 0; j < 32; ++j)
        wh[j] = *(const bf16x8*)(wswz + ((size_t)((16 + j) * 64 + cg * 4 + wv) * 64 + lane) * 8);

    __syncthreads();

    // ---- x A-frag prefetch for t=0
    const unsigned short* xbase = xb + (size_t)(b0 + m16) * S_ * DIN + q * 8;
    bf16x8 xf[16];
#pragma unroll
    for (int j = 0; j < 16; ++j)
        xf[j] = *(const bf16x8*)(xbase + j * 32);

    const int col = c0 + wv * 16 + (lane & 15);   // this lane's output column
    const int r0 = (lane >> 4) * 4;               // first of 4 output rows
    const float bias_c = bias[col];

    for (int t = 0; t < S_; ++t) {
        // ---- x-part MFMAs (independent of peers; xf prefetched last step)
        f32x4 acc0 = {0.f, 0.f, 0.f, 0.f}, acc1 = {0.f, 0.f, 0.f, 0.f};
#pragma unroll
        for (int j = 0; j < 16; ++j) {
            bf16x8 bb = *(const bf16x8*)(ldsX + ((j * 4 + wv) * 64 + lane) * 8);
            if (j & 1) acc1 = __builtin_amdgcn_mfma_f32_16x16x32_bf16(xf[j], bb, acc1, 0, 0, 0);
            else       acc0 = __builtin_amdgcn_mfma_f32_16x16x32_bf16(xf[j], bb, acc0, 0, 0, 0);
        }

        // ---- wait for h_{t-1}: each wave ballots 64 producer-wave flags, with backoff
        if (t > 0) {
            const int* fp = flags + (((size_t)bg * S_ + (t - 1)) << 6) + lane;
            for (;;) {
                int f = __hip_atomic_load(fp, __ATOMIC_RELAXED, __HIP_MEMORY_SCOPE_AGENT);
                if (__ballot(f == 0) == 0) break;
                __builtin_amdgcn_s_sleep(1);
            }
            __builtin_amdgcn_fence(__ATOMIC_ACQUIRE, "agent");
        }

        // ---- gather h_{t-1} -> LDS double buffer (cooperative, 16 ull/thread)
        unsigned short* hb = ldsH + (t & 1) * H_BUF;
        if (t == 0) {
#pragma unroll
            for (int i = 0; i < 16; ++i) {
                int u = i * 256 + tid;
                int row = u >> 8, cu = u & 255;       // cu indexes 4 bf16
                float4 v = *(const float4*)(h0 + (size_t)(b0 + row) * DH + cu * 4);
                ull pk = (ull)f2bf(v.x) | ((ull)f2bf(v.y) << 16) |
                         ((ull)f2bf(v.z) << 32) | ((ull)f2bf(v.w) << 48);
                *(ull*)(hb + row * H_PITCH + cu * 4) = pk;
            }
        } else {
            const ull* rg = (const ull*)(ring + ((t - 1) & 1) * (B_ * DH));
            ull hv[16];
#pragma unroll
            for (int i = 0; i < 16; ++i) {            // issue all loads first
                int u = i * 256 + tid;
                int row = u >> 8, cu = u & 255;
                hv[i] = __hip_atomic_load(rg + (size_t)(b0 + row) * 256 + cu,
                                          __ATOMIC_RELAXED, __HIP_MEMORY_SCOPE_AGENT);
            }
#pragma unroll
            for (int i = 0; i < 16; ++i) {
                int u = i * 256 + tid;
                int row = u >> 8, cu = u & 255;
                *(ull*)(hb + row * H_PITCH + cu * 4) = hv[i];
            }
        }
        __syncthreads();   // only barrier per step

        // ---- h-part MFMAs: full K per wave, own n-tile, no cross-wave reduction
#pragma unroll
        for (int j = 0; j < 32; ++j) {
            bf16x8 a = *(const bf16x8*)(hb + m16 * H_PITCH + j * 32 + q * 8);
            if (j & 1) acc1 = __builtin_amdgcn_mfma_f32_16x16x32_bf16(a, wh[j], acc1, 0, 0, 0);
            else       acc0 = __builtin_amdgcn_mfma_f32_16x16x32_bf16(a, wh[j], acc0, 0, 0, 0);
        }

        // ---- epilogue: bias + tanh; publish ring (atomic), then flag (release)
        float v[4];
        unsigned short* rw = ring + (t & 1) * (B_ * DH);
#pragma unroll
        for (int i = 0; i < 4; ++i) {
            v[i] = fast_tanh(acc0[i] + acc1[i] + bias_c);
            __hip_atomic_store(rw + (size_t)(b0 + r0 + i) * DH + col, f2bf(v[i]),
                               __ATOMIC_RELAXED, __HIP_MEMORY_SCOPE_AGENT);
        }
        if (lane == 0)   // wave-level release: waitcnt drains all 64 lanes' stores
            __hip_atomic_store(flags + (((size_t)bg * S_ + t) << 6) + cg * 4 + wv, 1,
                               __ATOMIC_RELEASE, __HIP_MEMORY_SCOPE_AGENT);

        // ---- off the critical path: out stores (nontemporal) + next x prefetch
#pragma unroll
        for (int i = 0; i < 4; ++i)
            __builtin_nontemporal_store(v[i],
                out + ((size_t)(b0 + r0 + i) * S_ + t) * DH + col);
        if (t == S_ - 1) {
#pragma unroll
            for (int i = 0; i < 4; ++i)
                __builtin_nontemporal_store(v[i],
                    out + (size_t)B_ * S_ * DH + (size_t)(b0 + r0 + i) * DH + col);
        }
        if (t < S_ - 1) {
            const unsigned short* xp = xbase + (size_t)(t + 1) * DIN;
#pragma unroll
            for (int j = 0; j < 16; ++j)
                xf[j] = *(const bf16x8*)(xp + j * 32);
        }
    }
}

extern "C" void kernel_launch(void* const* d_in, const int* in_sizes, int n_in,
                              void* d_out, int out_size, void* d_ws, size_t ws_size,
                              hipStream_t stream) {
    const float* x  = (const float*)d_in[0];   // [64][512][512]
    const float* h0 = (const float*)d_in[1];   // [64][1024]
    const float* W  = (const float*)d_in[2];   // [1536][1024]
    const float* b  = (const float*)d_in[3];   // [1024]
    float* out = (float*)d_out;

    // workspace layout
    char* ws = (char*)d_ws;
    int* flags = (int*)ws;                                          // 512 KB
    unsigned short* ring = (unsigned short*)(ws + (512 << 10));     // 256 KB
    unsigned short* xb = (unsigned short*)(ws + (768 << 10));       // 32 MB
    unsigned short* wswz = xb + (size_t)B_ * S_ * DIN;              // 3 MB

    (void)hipFuncSetAttribute((const void*)k_rnn,
                              hipFuncAttributeMaxDynamicSharedMemorySize,
                              SMEM_BYTES);

    hipMemsetAsync(flags, 0, NBG * S_ * 64 * sizeof(int), stream);
    k_cvt_bf16<<<(B_ * S_ * DIN / 4 + 255) / 256, 256, 0, stream>>>(x, xb, B_ * S_ * DIN / 4);
    k_swz_w<<<(NKC * 64 * 64) / 256, 256, 0, stream>>>(W, wswz);
    k_rnn<<<NBG * NCG, 256, SMEM_BYTES, stream>>>(xb, wswz, h0, b, out, ring, flags);
}